// Round 8
// baseline (1228.494 us; speedup 1.0000x reference)
//
#include <hip/hip_runtime.h>
#include <hip/hip_bf16.h>

// GCN_5016521802361: 2x SAGEConv(aggr='lstm', project=True), N=50000, D=16, F=128, C=40.
// Round 8: (1) Y stored column-PERMUTED so lstm stage-reads are 4x conflict-free
// ds_read_b128 per thread (p = w*128+q*32+g*8+hl*4+r); (2) lstm occupancy 3 blocks/CU;
// (3) row-local GEMM chains fused: x->xp->Y and lin1->xp2->Y2 single kernels (xp never
// hits HBM), 12 dispatches -> 7.

typedef __hip_bfloat16 bf16;
typedef __attribute__((ext_vector_type(8))) short short8;
typedef __attribute__((ext_vector_type(4))) short short4v;
typedef __attribute__((ext_vector_type(4))) float floatx4;

__device__ __forceinline__ float bf2f(bf16 v) { return __bfloat162float(v); }
__device__ __forceinline__ bf16  f2bf(float v) { return __float2bfloat16(v); }
__device__ __forceinline__ float bfs2f(short s) {
    union { float f; unsigned u; } v; v.u = ((unsigned)(unsigned short)s) << 16; return v.f;
}
__device__ __forceinline__ short f2bfs(float v) {
    bf16 b = __float2bfloat16(v); return *(short*)&b;
}

// merged-rcp LSTM cell update (r6, absmax-neutral)
__device__ __forceinline__ float cell(float i_, float f_, float g_, float o_, float& c) {
    float ei = __expf(-i_), ef = __expf(-f_), eg = __expf(2.f * g_);
    float cn = c * __builtin_amdgcn_rcpf(1.f + ef)
             + (eg - 1.f) * __builtin_amdgcn_rcpf((1.f + ei) * (eg + 1.f));
    c = cn;
    float ec = __expf(2.f * cn), eo = __expf(-o_);
    return (ec - 1.f) * __builtin_amdgcn_rcpf((ec + 1.f) * (1.f + eo));
}

// Y column permutation: cg (= gate*128 + hidden) -> p = w*128 + q*32 + g*8 + hl*4 + r
__device__ __forceinline__ int ypermute(int cg) {
    int g = cg >> 7, hid = cg & 127;
    return ((hid >> 5) << 7) | (((hid >> 2) & 3) << 5) | (g << 3) | (((hid >> 4) & 1) << 2) | (hid & 3);
}

// direct global->LDS DMA, 16B per lane (global_load_lds_dwordx4)
__device__ __forceinline__ void row_dma(const bf16* gp, void* lp) {
    __builtin_amdgcn_global_load_lds(
        (const __attribute__((address_space(1))) void*)gp,
        (__attribute__((address_space(3))) void*)lp, 16, 0, 0);
}

__global__ void detect_dtype(const unsigned short* __restrict__ xb, int* __restrict__ flag) {
    int cnt = 0;
    for (int i = threadIdx.x; i < 1024; i += 64) {
        int e = (xb[i] >> 7) & 0xFF;
        cnt += (e >= 0xC8);
    }
#pragma unroll
    for (int off = 32; off; off >>= 1) cnt += __shfl_down(cnt, off);
    if (threadIdx.x == 0) *flag = (cnt >= 16) ? 1 : 0;   // 1 => inputs are float32
}

struct Cvt { const void* src; bf16* dst; int n; };
struct CvtAll { Cvt t[19]; };

__global__ void convert_inputs(CvtAll ca, const int* __restrict__ flag) {
    const bool isf32 = (*flag != 0);
    const int stride = gridDim.x * blockDim.x;
    const int tid0 = blockIdx.x * blockDim.x + threadIdx.x;
#pragma unroll 1
    for (int k = 0; k < 19; k++) {
        const int n = ca.t[k].n;
        const float* sf = (const float*)ca.t[k].src;
        const bf16*  sb = (const bf16*)ca.t[k].src;
        bf16* d = ca.t[k].dst;
        for (int i = tid0; i < n; i += stride)
            d[i] = isf32 ? f2bf(sf[i]) : sb[i];
    }
}

// generic (kept for the final lin2 layer)
template <int NCT, bool RELU, bool BIAS2, bool DUAL, bool OUTF>
__global__ __launch_bounds__(256, 2) void gemm_bias(
    const bf16* __restrict__ A, const bf16* __restrict__ B,
    const bf16* __restrict__ bias, const bf16* __restrict__ bias2,
    const bf16* __restrict__ A2, const bf16* __restrict__ B2,
    void* __restrict__ Cv, const int* __restrict__ oflag,
    int N, int nbt, int ldc)
{
    const int tid = threadIdx.x;
    const int w = tid >> 6, l = tid & 63, q = l >> 4, lid = l & 15;
    const int rowbase = blockIdx.x * 64 + w * 16;
    const int colslice = blockIdx.y * (NCT * 16);

    int arow = rowbase + lid;
    if (arow >= N) arow = N - 1;

    floatx4 acc[NCT];
#pragma unroll
    for (int ct = 0; ct < NCT; ct++) acc[ct] = (floatx4)(0.f);

    short8 bfrag[NCT][4];
#pragma unroll
    for (int ct = 0; ct < NCT; ct++) {
        int j = colslice + ct * 16 + lid;
        if (j >= nbt) j = nbt - 1;
#pragma unroll
        for (int kt = 0; kt < 4; kt++)
            bfrag[ct][kt] = *(const short8*)(B + (size_t)j * 128 + kt * 32 + q * 8);
    }
#pragma unroll
    for (int kt = 0; kt < 4; kt++) {
        short8 af = *(const short8*)(A + (size_t)arow * 128 + kt * 32 + q * 8);
#pragma unroll
        for (int ct = 0; ct < NCT; ct++)
            acc[ct] = __builtin_amdgcn_mfma_f32_16x16x32_bf16(af, bfrag[ct][kt], acc[ct], 0, 0, 0);
    }
    if constexpr (DUAL) {
#pragma unroll
        for (int ct = 0; ct < NCT; ct++) {
            int j = colslice + ct * 16 + lid;
            if (j >= nbt) j = nbt - 1;
#pragma unroll
            for (int kt = 0; kt < 4; kt++)
                bfrag[ct][kt] = *(const short8*)(B2 + (size_t)j * 128 + kt * 32 + q * 8);
        }
#pragma unroll
        for (int kt = 0; kt < 4; kt++) {
            short8 af = *(const short8*)(A2 + (size_t)arow * 128 + kt * 32 + q * 8);
#pragma unroll
            for (int ct = 0; ct < NCT; ct++)
                acc[ct] = __builtin_amdgcn_mfma_f32_16x16x32_bf16(af, bfrag[ct][kt], acc[ct], 0, 0, 0);
        }
    }
    bool of32 = false;
    if constexpr (OUTF) of32 = (*oflag != 0);
#pragma unroll
    for (int ct = 0; ct < NCT; ct++) {
        int cg = colslice + ct * 16 + lid;
        int cb = cg < nbt ? cg : nbt - 1;
        float bv = bf2f(bias[cb]);
        if constexpr (BIAS2) bv += bf2f(bias2[cb]);
#pragma unroll
        for (int r = 0; r < 4; r++) {
            int row = rowbase + q * 4 + r;
            float v = acc[ct][r] + bv;
            if constexpr (RELU) v = fmaxf(v, 0.f);
            if (row < N && cg < nbt) {
                size_t idx = (size_t)row * ldc + cg;
                if constexpr (OUTF) {
                    if (of32) ((float*)Cv)[idx] = v;
                    else      ((bf16*)Cv)[idx] = f2bf(v);
                } else {
                    ((bf16*)Cv)[idx] = f2bf(v);
                }
            }
        }
    }
}

// ---------------------------------------------------------------------------
// Fused chain, layer entry:  Y = (relu(X@Wp^T+bp)) @ Wih^T + bih + bhh, permuted.
// 64 rows/block; xp tile lives only in LDS.
// ---------------------------------------------------------------------------
__global__ __launch_bounds__(256, 2) void fused_xp_y(
    const bf16* __restrict__ X, const bf16* __restrict__ Wp, const bf16* __restrict__ bp,
    const bf16* __restrict__ Wih, const bf16* __restrict__ bih, const bf16* __restrict__ bhh,
    bf16* __restrict__ Yout, int N)
{
    __shared__ bf16 T[64][136];
    const int tid = threadIdx.x;
    const int w = tid >> 6, l = tid & 63, q = l >> 4, lid = l & 15;
    const int rowbase = blockIdx.x * 64;

    int arow = rowbase + w * 16 + lid;
    if (arow >= N) arow = N - 1;

    floatx4 acc[8];
    short8 bfrag[8][4];

    // ---- stage A: xp = relu(X@Wp^T + bp) -> T ----
#pragma unroll
    for (int ct = 0; ct < 8; ct++) acc[ct] = (floatx4)(0.f);
#pragma unroll
    for (int ct = 0; ct < 8; ct++) {
        int j = ct * 16 + lid;
#pragma unroll
        for (int kt = 0; kt < 4; kt++)
            bfrag[ct][kt] = *(const short8*)(Wp + (size_t)j * 128 + kt * 32 + q * 8);
    }
#pragma unroll
    for (int kt = 0; kt < 4; kt++) {
        short8 af = *(const short8*)(X + (size_t)arow * 128 + kt * 32 + q * 8);
#pragma unroll
        for (int ct = 0; ct < 8; ct++)
            acc[ct] = __builtin_amdgcn_mfma_f32_16x16x32_bf16(af, bfrag[ct][kt], acc[ct], 0, 0, 0);
    }
#pragma unroll
    for (int ct = 0; ct < 8; ct++) {
        int col = ct * 16 + lid;
        float bv = bf2f(bp[col]);
#pragma unroll
        for (int r = 0; r < 4; r++)
            T[w * 16 + q * 4 + r][col] = f2bf(fmaxf(acc[ct][r] + bv, 0.f));
    }
    __syncthreads();

    // ---- stage B: Y chunks (128 cols each), A from T, permuted store ----
#pragma unroll 1
    for (int cc = 0; cc < 4; cc++) {
#pragma unroll
        for (int ct = 0; ct < 8; ct++) {
            int j = cc * 128 + ct * 16 + lid;
#pragma unroll
            for (int kt = 0; kt < 4; kt++)
                bfrag[ct][kt] = *(const short8*)(Wih + (size_t)j * 128 + kt * 32 + q * 8);
        }
#pragma unroll
        for (int ct = 0; ct < 8; ct++) acc[ct] = (floatx4)(0.f);
#pragma unroll
        for (int kt = 0; kt < 4; kt++) {
            short8 af = *(const short8*)&T[w * 16 + lid][kt * 32 + q * 8];
#pragma unroll
            for (int ct = 0; ct < 8; ct++)
                acc[ct] = __builtin_amdgcn_mfma_f32_16x16x32_bf16(af, bfrag[ct][kt], acc[ct], 0, 0, 0);
        }
#pragma unroll
        for (int ct = 0; ct < 8; ct++) {
            int cg = cc * 128 + ct * 16 + lid;
            float bv = bf2f(bih[cg]) + bf2f(bhh[cg]);
            int p = ypermute(cg);
#pragma unroll
            for (int r = 0; r < 4; r++) {
                int row = rowbase + w * 16 + q * 4 + r;
                if (row < N) Yout[(size_t)row * 512 + p] = f2bf(acc[ct][r] + bv);
            }
        }
    }
}

// ---------------------------------------------------------------------------
// Fused chain, between layers:
//   h1 = relu(aggr@Wl^T + bl + X@Wr^T)      (written to global AND kept in LDS)
//   xp2 = relu(h1@Wp2^T + bp2)              (LDS only)
//   Y2  = xp2@Wih2^T + bih2 + bhh2          (permuted store)
// ---------------------------------------------------------------------------
__global__ __launch_bounds__(256, 2) void fused_lin_xp_y(
    const bf16* __restrict__ aggr, const bf16* __restrict__ Wl, const bf16* __restrict__ bl,
    const bf16* __restrict__ X, const bf16* __restrict__ Wr,
    bf16* __restrict__ h1out,
    const bf16* __restrict__ Wp2, const bf16* __restrict__ bp2,
    const bf16* __restrict__ Wih2, const bf16* __restrict__ bih2, const bf16* __restrict__ bhh2,
    bf16* __restrict__ Yout, int N)
{
    __shared__ bf16 T1[64][136];
    __shared__ bf16 T2[64][136];
    const int tid = threadIdx.x;
    const int w = tid >> 6, l = tid & 63, q = l >> 4, lid = l & 15;
    const int rowbase = blockIdx.x * 64;

    int arow = rowbase + w * 16 + lid;
    if (arow >= N) arow = N - 1;

    floatx4 acc[8];
    short8 bfrag[8][4];

    // ---- stage A: h1 = relu(aggr@Wl^T + X@Wr^T + bl) -> T1 + global ----
#pragma unroll
    for (int ct = 0; ct < 8; ct++) acc[ct] = (floatx4)(0.f);
#pragma unroll
    for (int ct = 0; ct < 8; ct++) {
        int j = ct * 16 + lid;
#pragma unroll
        for (int kt = 0; kt < 4; kt++)
            bfrag[ct][kt] = *(const short8*)(Wl + (size_t)j * 128 + kt * 32 + q * 8);
    }
#pragma unroll
    for (int kt = 0; kt < 4; kt++) {
        short8 af = *(const short8*)(aggr + (size_t)arow * 128 + kt * 32 + q * 8);
#pragma unroll
        for (int ct = 0; ct < 8; ct++)
            acc[ct] = __builtin_amdgcn_mfma_f32_16x16x32_bf16(af, bfrag[ct][kt], acc[ct], 0, 0, 0);
    }
#pragma unroll
    for (int ct = 0; ct < 8; ct++) {
        int j = ct * 16 + lid;
#pragma unroll
        for (int kt = 0; kt < 4; kt++)
            bfrag[ct][kt] = *(const short8*)(Wr + (size_t)j * 128 + kt * 32 + q * 8);
    }
#pragma unroll
    for (int kt = 0; kt < 4; kt++) {
        short8 af = *(const short8*)(X + (size_t)arow * 128 + kt * 32 + q * 8);
#pragma unroll
        for (int ct = 0; ct < 8; ct++)
            acc[ct] = __builtin_amdgcn_mfma_f32_16x16x32_bf16(af, bfrag[ct][kt], acc[ct], 0, 0, 0);
    }
#pragma unroll
    for (int ct = 0; ct < 8; ct++) {
        int col = ct * 16 + lid;
        float bv = bf2f(bl[col]);
#pragma unroll
        for (int r = 0; r < 4; r++) {
            int rl = w * 16 + q * 4 + r;
            bf16 hv = f2bf(fmaxf(acc[ct][r] + bv, 0.f));
            T1[rl][col] = hv;
            int row = rowbase + rl;
            if (row < N) h1out[(size_t)row * 128 + col] = hv;
        }
    }
    __syncthreads();

    // ---- stage B: xp2 = relu(T1@Wp2^T + bp2) -> T2 ----
#pragma unroll
    for (int ct = 0; ct < 8; ct++) {
        int j = ct * 16 + lid;
#pragma unroll
        for (int kt = 0; kt < 4; kt++)
            bfrag[ct][kt] = *(const short8*)(Wp2 + (size_t)j * 128 + kt * 32 + q * 8);
    }
#pragma unroll
    for (int ct = 0; ct < 8; ct++) acc[ct] = (floatx4)(0.f);
#pragma unroll
    for (int kt = 0; kt < 4; kt++) {
        short8 af = *(const short8*)&T1[w * 16 + lid][kt * 32 + q * 8];
#pragma unroll
        for (int ct = 0; ct < 8; ct++)
            acc[ct] = __builtin_amdgcn_mfma_f32_16x16x32_bf16(af, bfrag[ct][kt], acc[ct], 0, 0, 0);
    }
#pragma unroll
    for (int ct = 0; ct < 8; ct++) {
        int col = ct * 16 + lid;
        float bv = bf2f(bp2[col]);
#pragma unroll
        for (int r = 0; r < 4; r++)
            T2[w * 16 + q * 4 + r][col] = f2bf(fmaxf(acc[ct][r] + bv, 0.f));
    }
    __syncthreads();

    // ---- stage C: Y2 chunks from T2, permuted store ----
#pragma unroll 1
    for (int cc = 0; cc < 4; cc++) {
#pragma unroll
        for (int ct = 0; ct < 8; ct++) {
            int j = cc * 128 + ct * 16 + lid;
#pragma unroll
            for (int kt = 0; kt < 4; kt++)
                bfrag[ct][kt] = *(const short8*)(Wih2 + (size_t)j * 128 + kt * 32 + q * 8);
        }
#pragma unroll
        for (int ct = 0; ct < 8; ct++) acc[ct] = (floatx4)(0.f);
#pragma unroll
        for (int kt = 0; kt < 4; kt++) {
            short8 af = *(const short8*)&T2[w * 16 + lid][kt * 32 + q * 8];
#pragma unroll
            for (int ct = 0; ct < 8; ct++)
                acc[ct] = __builtin_amdgcn_mfma_f32_16x16x32_bf16(af, bfrag[ct][kt], acc[ct], 0, 0, 0);
        }
#pragma unroll
        for (int ct = 0; ct < 8; ct++) {
            int cg = cc * 128 + ct * 16 + lid;
            float bv = bf2f(bih2[cg]) + bf2f(bhh2[cg]);
            int p = ypermute(cg);
#pragma unroll
            for (int r = 0; r < 4; r++) {
                int row = rowbase + w * 16 + q * 4 + r;
                if (row < N) Yout[(size_t)row * 512 + p] = f2bf(acc[ct][r] + bv);
            }
        }
    }
}

// ---------------------------------------------------------------------------
// LSTM neighbor aggregation (permuted Y). Block = 16 nodes, 256 thr, 3 blocks/CU.
// Per step: wave w DMAs rows srcl[t+1][4j+w] (1KB each) into the LDS stage;
// consumer thread reads ONE conflict-free ds_read_b128 per gate g:
//   stage[lid][w*128+q*32+g*8 .. +7] = {hl0 r0..3, hl1 r0..3}.
// ---------------------------------------------------------------------------
__global__ __launch_bounds__(256, 3) void lstm_aggr(
    const bf16* __restrict__ Y,     // [N,512] PERMUTED pre-activations
    const int* __restrict__ esrc,   // [N,16]
    const bf16* __restrict__ Whh,   // [512,128]
    bf16* __restrict__ aggr,        // [N,128] out: final h
    int N)
{
    __shared__ alignas(16) short stage[2][16][520];  // 1040B row stride
    __shared__ alignas(16) bf16 hb[2][16][136];
    __shared__ int srcl[16][16];    // [t][node]

    const int tid = threadIdx.x;
    const int w = tid >> 6, l = tid & 63, q = l >> 4, lid = l & 15;
    const int nodebase = blockIdx.x * 16;   // N = 50000 = 3125*16, exact

    {
        int node = tid >> 4, t = tid & 15;
        srcl[t][node] = esrc[(size_t)(nodebase + node) * 16 + t];
    }
    for (int i = tid; i < 16 * 136; i += 256) ((short*)hb[0])[i] = 0;

    // Whh A-fragments: wf[hl][g][kt]; A-row = gatecol = (2w+hl+8g)*16 + lid
    short8 wf[2][4][4];
#pragma unroll
    for (int hl = 0; hl < 2; hl++)
#pragma unroll
        for (int g = 0; g < 4; g++) {
            int gc = (2 * w + hl + 8 * g) * 16 + lid;
#pragma unroll
            for (int kt = 0; kt < 4; kt++)
                wf[hl][g][kt] = *(const short8*)(Whh + (size_t)gc * 128 + kt * 32 + q * 8);
        }

    float c[2][4];
#pragma unroll
    for (int hl = 0; hl < 2; hl++)
#pragma unroll
        for (int r = 0; r < 4; r++) c[hl][r] = 0.f;

    __syncthreads();   // srcl visible before first DMA

    // prologue: DMA t=0 rows into stage[0] (wave w fetches rows 4j+w)
#pragma unroll
    for (int j = 0; j < 4; j++) {
        int r = 4 * j + w;
        int s = srcl[0][r];
        row_dma(Y + (size_t)s * 512 + l * 8, &stage[0][r][0]);
    }
    __syncthreads();   // drains vmcnt: stage[0] landed

#pragma unroll 2
    for (int t = 0; t < 16; t++) {
        const int cb = t & 1, nb = cb ^ 1;

        // issue DMA for t+1 first — in flight across the whole step
        if (t < 15) {
#pragma unroll
            for (int j = 0; j < 4; j++) {
                int r = 4 * j + w;
                int s = srcl[t + 1][r];
                row_dma(Y + (size_t)s * 512 + l * 8, &stage[nb][r][0]);
            }
        }

        // acc init: one b128 per gate (conflict-free), values {hl0 r0..3, hl1 r0..3}
        floatx4 acc[2][4];
#pragma unroll
        for (int g = 0; g < 4; g++) {
            short8 yv = *(const short8*)&stage[cb][lid][w * 128 + q * 32 + g * 8];
#pragma unroll
            for (int hl = 0; hl < 2; hl++)
#pragma unroll
                for (int r = 0; r < 4; r++)
                    acc[hl][g][r] = bfs2f(yv[hl * 4 + r]);
        }

        // G^T += Whh * h^T : B-frag = h[node=lid][k] via ds_read_b128
#pragma unroll
        for (int kt = 0; kt < 4; kt++) {
            short8 bh = *(const short8*)&hb[cb][lid][kt * 32 + q * 8];
#pragma unroll
            for (int hl = 0; hl < 2; hl++)
#pragma unroll
                for (int g = 0; g < 4; g++)
                    acc[hl][g] = __builtin_amdgcn_mfma_f32_16x16x32_bf16(wf[hl][g][kt], bh, acc[hl][g], 0, 0, 0);
        }

        // gates; h' cols hc = 32w+16hl+q*4+r for node lid
#pragma unroll
        for (int hl = 0; hl < 2; hl++) {
            short4v hv;
#pragma unroll
            for (int r = 0; r < 4; r++)
                hv[r] = f2bfs(cell(acc[hl][0][r], acc[hl][1][r], acc[hl][2][r], acc[hl][3][r], c[hl][r]));
            if (t < 15) *(short4v*)&hb[nb][lid][32 * w + 16 * hl + 4 * q] = hv;
            else        *(short4v*)(aggr + (size_t)(nodebase + lid) * 128 + 32 * w + 16 * hl + 4 * q) = hv;
        }

        __syncthreads();   // orders hb swap AND guarantees t+1 DMA landed
    }
}

extern "C" void kernel_launch(void* const* d_in, const int* in_sizes, int n_in,
                              void* d_out, int out_size, void* d_ws, size_t ws_size,
                              hipStream_t stream)
{
    const int N = 50000;
    const int* es = (const int*)d_in[1];
    char* ws = (char*)d_ws;

    // converted bf16 copies of the 19 used float tensors @[0,15MB)
    static const int idxs[19] = {0, 8,9,10,11,12,13,14,15,16, 17,18,19,20,21,22,23,24,25};
    bf16* conv[19];
    size_t off = 0;
    CvtAll ca;
    for (int k = 0; k < 19; k++) {
        conv[k] = (bf16*)ws + off;
        ca.t[k].src = d_in[idxs[k]];
        ca.t[k].dst = conv[k];
        ca.t[k].n = in_sizes[idxs[k]];
        off += (size_t)((in_sizes[idxs[k]] + 63) & ~63);
    }
    int* flag = (int*)(ws + ((size_t)15 << 20));
    bf16* aggr = (bf16*)(ws + ((size_t)16 << 20));   // [N,128]
    bf16* Y    = (bf16*)(ws + ((size_t)30 << 20));   // [N,512] permuted
    bf16* h1   = (bf16*)(ws + ((size_t)84 << 20));   // [N,128]

    const bf16 *xc  = conv[0];
    const bf16 *Wp1 = conv[1],  *bp1 = conv[2],  *Wih1 = conv[3],  *Whh1 = conv[4];
    const bf16 *bih1 = conv[5], *bhh1 = conv[6], *Wl1 = conv[7],   *bl1 = conv[8],  *Wr1 = conv[9];
    const bf16 *Wp2 = conv[10], *bp2 = conv[11], *Wih2 = conv[12], *Whh2 = conv[13];
    const bf16 *bih2 = conv[14], *bhh2 = conv[15], *Wl2 = conv[16], *bl2 = conv[17], *Wr2 = conv[18];

    dim3 blk(256);
    const int gx = (N + 63) / 64;    // 782
    const int gl = N / 16;           // 3125 (exact)

    detect_dtype<<<dim3(1), dim3(64), 0, stream>>>((const unsigned short*)d_in[0], flag);
    convert_inputs<<<dim3(1024), blk, 0, stream>>>(ca, flag);

    // ---- layer 1 ----
    fused_xp_y<<<dim3(gx), blk, 0, stream>>>(xc, Wp1, bp1, Wih1, bih1, bhh1, Y, N);
    lstm_aggr<<<dim3(gl), blk, 0, stream>>>(Y, es, Whh1, aggr, N);

    // ---- between layers: lin1 -> xp2 -> Y2 ----
    fused_lin_xp_y<<<dim3(gx), blk, 0, stream>>>(
        aggr, Wl1, bl1, xc, Wr1, h1, Wp2, bp2, Wih2, bih2, bhh2, Y, N);
    lstm_aggr<<<dim3(gl), blk, 0, stream>>>(Y, es, Whh2, aggr, N);

    // ---- final: out = lin_l2(aggr) + bl2 + lin_r2(h1) ----
    gemm_bias<3, false, false, true, true><<<dim3(gx, 1), blk, 0, stream>>>(
        aggr, Wl2, bl2, nullptr, h1, Wr2, d_out, flag, N, 40, 40);
}

// Round 9
// 765.599 us; speedup vs baseline: 1.6046x; 1.6046x over previous
//
#include <hip/hip_runtime.h>
#include <hip/hip_bf16.h>

// GCN_5016521802361: 2x SAGEConv(aggr='lstm', project=True), N=50000, D=16, F=128, C=40.
// Round 9: revert lstm occupancy to 2 blocks/CU (r8's launch_bounds(256,3) forced a
// ~170-VGPR cap -> wf spilled to scratch: FETCH 376MB->1.27GB, WRITE 12.5->156MB).
// Everything else kept from r8: permuted Y (conflict-free b128 stage reads), row-DMA
// gather, fused x->xp->Y and lin1->xp2->Y2 chains.

typedef __hip_bfloat16 bf16;
typedef __attribute__((ext_vector_type(8))) short short8;
typedef __attribute__((ext_vector_type(4))) short short4v;
typedef __attribute__((ext_vector_type(4))) float floatx4;

__device__ __forceinline__ float bf2f(bf16 v) { return __bfloat162float(v); }
__device__ __forceinline__ bf16  f2bf(float v) { return __float2bfloat16(v); }
__device__ __forceinline__ float bfs2f(short s) {
    union { float f; unsigned u; } v; v.u = ((unsigned)(unsigned short)s) << 16; return v.f;
}
__device__ __forceinline__ short f2bfs(float v) {
    bf16 b = __float2bfloat16(v); return *(short*)&b;
}

// merged-rcp LSTM cell update (r6, absmax-neutral)
__device__ __forceinline__ float cell(float i_, float f_, float g_, float o_, float& c) {
    float ei = __expf(-i_), ef = __expf(-f_), eg = __expf(2.f * g_);
    float cn = c * __builtin_amdgcn_rcpf(1.f + ef)
             + (eg - 1.f) * __builtin_amdgcn_rcpf((1.f + ei) * (eg + 1.f));
    c = cn;
    float ec = __expf(2.f * cn), eo = __expf(-o_);
    return (ec - 1.f) * __builtin_amdgcn_rcpf((ec + 1.f) * (1.f + eo));
}

// Y column permutation: cg (= gate*128 + hidden) -> p = w*128 + q*32 + g*8 + hl*4 + r
__device__ __forceinline__ int ypermute(int cg) {
    int g = cg >> 7, hid = cg & 127;
    return ((hid >> 5) << 7) | (((hid >> 2) & 3) << 5) | (g << 3) | (((hid >> 4) & 1) << 2) | (hid & 3);
}

// direct global->LDS DMA, 16B per lane (global_load_lds_dwordx4)
__device__ __forceinline__ void row_dma(const bf16* gp, void* lp) {
    __builtin_amdgcn_global_load_lds(
        (const __attribute__((address_space(1))) void*)gp,
        (__attribute__((address_space(3))) void*)lp, 16, 0, 0);
}

__global__ void detect_dtype(const unsigned short* __restrict__ xb, int* __restrict__ flag) {
    int cnt = 0;
    for (int i = threadIdx.x; i < 1024; i += 64) {
        int e = (xb[i] >> 7) & 0xFF;
        cnt += (e >= 0xC8);
    }
#pragma unroll
    for (int off = 32; off; off >>= 1) cnt += __shfl_down(cnt, off);
    if (threadIdx.x == 0) *flag = (cnt >= 16) ? 1 : 0;   // 1 => inputs are float32
}

struct Cvt { const void* src; bf16* dst; int n; };
struct CvtAll { Cvt t[19]; };

__global__ void convert_inputs(CvtAll ca, const int* __restrict__ flag) {
    const bool isf32 = (*flag != 0);
    const int stride = gridDim.x * blockDim.x;
    const int tid0 = blockIdx.x * blockDim.x + threadIdx.x;
#pragma unroll 1
    for (int k = 0; k < 19; k++) {
        const int n = ca.t[k].n;
        const float* sf = (const float*)ca.t[k].src;
        const bf16*  sb = (const bf16*)ca.t[k].src;
        bf16* d = ca.t[k].dst;
        for (int i = tid0; i < n; i += stride)
            d[i] = isf32 ? f2bf(sf[i]) : sb[i];
    }
}

// generic (kept for the final lin2 layer)
template <int NCT, bool RELU, bool BIAS2, bool DUAL, bool OUTF>
__global__ __launch_bounds__(256, 2) void gemm_bias(
    const bf16* __restrict__ A, const bf16* __restrict__ B,
    const bf16* __restrict__ bias, const bf16* __restrict__ bias2,
    const bf16* __restrict__ A2, const bf16* __restrict__ B2,
    void* __restrict__ Cv, const int* __restrict__ oflag,
    int N, int nbt, int ldc)
{
    const int tid = threadIdx.x;
    const int w = tid >> 6, l = tid & 63, q = l >> 4, lid = l & 15;
    const int rowbase = blockIdx.x * 64 + w * 16;
    const int colslice = blockIdx.y * (NCT * 16);

    int arow = rowbase + lid;
    if (arow >= N) arow = N - 1;

    floatx4 acc[NCT];
#pragma unroll
    for (int ct = 0; ct < NCT; ct++) acc[ct] = (floatx4)(0.f);

    short8 bfrag[NCT][4];
#pragma unroll
    for (int ct = 0; ct < NCT; ct++) {
        int j = colslice + ct * 16 + lid;
        if (j >= nbt) j = nbt - 1;
#pragma unroll
        for (int kt = 0; kt < 4; kt++)
            bfrag[ct][kt] = *(const short8*)(B + (size_t)j * 128 + kt * 32 + q * 8);
    }
#pragma unroll
    for (int kt = 0; kt < 4; kt++) {
        short8 af = *(const short8*)(A + (size_t)arow * 128 + kt * 32 + q * 8);
#pragma unroll
        for (int ct = 0; ct < NCT; ct++)
            acc[ct] = __builtin_amdgcn_mfma_f32_16x16x32_bf16(af, bfrag[ct][kt], acc[ct], 0, 0, 0);
    }
    if constexpr (DUAL) {
#pragma unroll
        for (int ct = 0; ct < NCT; ct++) {
            int j = colslice + ct * 16 + lid;
            if (j >= nbt) j = nbt - 1;
#pragma unroll
            for (int kt = 0; kt < 4; kt++)
                bfrag[ct][kt] = *(const short8*)(B2 + (size_t)j * 128 + kt * 32 + q * 8);
        }
#pragma unroll
        for (int kt = 0; kt < 4; kt++) {
            short8 af = *(const short8*)(A2 + (size_t)arow * 128 + kt * 32 + q * 8);
#pragma unroll
            for (int ct = 0; ct < NCT; ct++)
                acc[ct] = __builtin_amdgcn_mfma_f32_16x16x32_bf16(af, bfrag[ct][kt], acc[ct], 0, 0, 0);
        }
    }
    bool of32 = false;
    if constexpr (OUTF) of32 = (*oflag != 0);
#pragma unroll
    for (int ct = 0; ct < NCT; ct++) {
        int cg = colslice + ct * 16 + lid;
        int cb = cg < nbt ? cg : nbt - 1;
        float bv = bf2f(bias[cb]);
        if constexpr (BIAS2) bv += bf2f(bias2[cb]);
#pragma unroll
        for (int r = 0; r < 4; r++) {
            int row = rowbase + q * 4 + r;
            float v = acc[ct][r] + bv;
            if constexpr (RELU) v = fmaxf(v, 0.f);
            if (row < N && cg < nbt) {
                size_t idx = (size_t)row * ldc + cg;
                if constexpr (OUTF) {
                    if (of32) ((float*)Cv)[idx] = v;
                    else      ((bf16*)Cv)[idx] = f2bf(v);
                } else {
                    ((bf16*)Cv)[idx] = f2bf(v);
                }
            }
        }
    }
}

// ---------------------------------------------------------------------------
// Fused chain, layer entry:  Y = (relu(X@Wp^T+bp)) @ Wih^T + bih + bhh, permuted.
// ---------------------------------------------------------------------------
__global__ __launch_bounds__(256, 2) void fused_xp_y(
    const bf16* __restrict__ X, const bf16* __restrict__ Wp, const bf16* __restrict__ bp,
    const bf16* __restrict__ Wih, const bf16* __restrict__ bih, const bf16* __restrict__ bhh,
    bf16* __restrict__ Yout, int N)
{
    __shared__ bf16 T[64][136];
    const int tid = threadIdx.x;
    const int w = tid >> 6, l = tid & 63, q = l >> 4, lid = l & 15;
    const int rowbase = blockIdx.x * 64;

    int arow = rowbase + w * 16 + lid;
    if (arow >= N) arow = N - 1;

    floatx4 acc[8];
    short8 bfrag[8][4];

    // ---- stage A: xp = relu(X@Wp^T + bp) -> T ----
#pragma unroll
    for (int ct = 0; ct < 8; ct++) acc[ct] = (floatx4)(0.f);
#pragma unroll
    for (int ct = 0; ct < 8; ct++) {
        int j = ct * 16 + lid;
#pragma unroll
        for (int kt = 0; kt < 4; kt++)
            bfrag[ct][kt] = *(const short8*)(Wp + (size_t)j * 128 + kt * 32 + q * 8);
    }
#pragma unroll
    for (int kt = 0; kt < 4; kt++) {
        short8 af = *(const short8*)(X + (size_t)arow * 128 + kt * 32 + q * 8);
#pragma unroll
        for (int ct = 0; ct < 8; ct++)
            acc[ct] = __builtin_amdgcn_mfma_f32_16x16x32_bf16(af, bfrag[ct][kt], acc[ct], 0, 0, 0);
    }
#pragma unroll
    for (int ct = 0; ct < 8; ct++) {
        int col = ct * 16 + lid;
        float bv = bf2f(bp[col]);
#pragma unroll
        for (int r = 0; r < 4; r++)
            T[w * 16 + q * 4 + r][col] = f2bf(fmaxf(acc[ct][r] + bv, 0.f));
    }
    __syncthreads();

    // ---- stage B: Y chunks (128 cols each), A from T, permuted store ----
#pragma unroll 1
    for (int cc = 0; cc < 4; cc++) {
#pragma unroll
        for (int ct = 0; ct < 8; ct++) {
            int j = cc * 128 + ct * 16 + lid;
#pragma unroll
            for (int kt = 0; kt < 4; kt++)
                bfrag[ct][kt] = *(const short8*)(Wih + (size_t)j * 128 + kt * 32 + q * 8);
        }
#pragma unroll
        for (int ct = 0; ct < 8; ct++) acc[ct] = (floatx4)(0.f);
#pragma unroll
        for (int kt = 0; kt < 4; kt++) {
            short8 af = *(const short8*)&T[w * 16 + lid][kt * 32 + q * 8];
#pragma unroll
            for (int ct = 0; ct < 8; ct++)
                acc[ct] = __builtin_amdgcn_mfma_f32_16x16x32_bf16(af, bfrag[ct][kt], acc[ct], 0, 0, 0);
        }
#pragma unroll
        for (int ct = 0; ct < 8; ct++) {
            int cg = cc * 128 + ct * 16 + lid;
            float bv = bf2f(bih[cg]) + bf2f(bhh[cg]);
            int p = ypermute(cg);
#pragma unroll
            for (int r = 0; r < 4; r++) {
                int row = rowbase + w * 16 + q * 4 + r;
                if (row < N) Yout[(size_t)row * 512 + p] = f2bf(acc[ct][r] + bv);
            }
        }
    }
}

// ---------------------------------------------------------------------------
// Fused chain, between layers: h1 = relu(aggr@Wl^T+bl+X@Wr^T) (global+LDS);
// xp2 = relu(h1@Wp2^T+bp2) (LDS); Y2 = xp2@Wih2^T+bih2+bhh2 (permuted store).
// ---------------------------------------------------------------------------
__global__ __launch_bounds__(256, 2) void fused_lin_xp_y(
    const bf16* __restrict__ aggr, const bf16* __restrict__ Wl, const bf16* __restrict__ bl,
    const bf16* __restrict__ X, const bf16* __restrict__ Wr,
    bf16* __restrict__ h1out,
    const bf16* __restrict__ Wp2, const bf16* __restrict__ bp2,
    const bf16* __restrict__ Wih2, const bf16* __restrict__ bih2, const bf16* __restrict__ bhh2,
    bf16* __restrict__ Yout, int N)
{
    __shared__ bf16 T1[64][136];
    __shared__ bf16 T2[64][136];
    const int tid = threadIdx.x;
    const int w = tid >> 6, l = tid & 63, q = l >> 4, lid = l & 15;
    const int rowbase = blockIdx.x * 64;

    int arow = rowbase + w * 16 + lid;
    if (arow >= N) arow = N - 1;

    floatx4 acc[8];
    short8 bfrag[8][4];

    // ---- stage A: h1 = relu(aggr@Wl^T + X@Wr^T + bl) -> T1 + global ----
#pragma unroll
    for (int ct = 0; ct < 8; ct++) acc[ct] = (floatx4)(0.f);
#pragma unroll
    for (int ct = 0; ct < 8; ct++) {
        int j = ct * 16 + lid;
#pragma unroll
        for (int kt = 0; kt < 4; kt++)
            bfrag[ct][kt] = *(const short8*)(Wl + (size_t)j * 128 + kt * 32 + q * 8);
    }
#pragma unroll
    for (int kt = 0; kt < 4; kt++) {
        short8 af = *(const short8*)(aggr + (size_t)arow * 128 + kt * 32 + q * 8);
#pragma unroll
        for (int ct = 0; ct < 8; ct++)
            acc[ct] = __builtin_amdgcn_mfma_f32_16x16x32_bf16(af, bfrag[ct][kt], acc[ct], 0, 0, 0);
    }
#pragma unroll
    for (int ct = 0; ct < 8; ct++) {
        int j = ct * 16 + lid;
#pragma unroll
        for (int kt = 0; kt < 4; kt++)
            bfrag[ct][kt] = *(const short8*)(Wr + (size_t)j * 128 + kt * 32 + q * 8);
    }
#pragma unroll
    for (int kt = 0; kt < 4; kt++) {
        short8 af = *(const short8*)(X + (size_t)arow * 128 + kt * 32 + q * 8);
#pragma unroll
        for (int ct = 0; ct < 8; ct++)
            acc[ct] = __builtin_amdgcn_mfma_f32_16x16x32_bf16(af, bfrag[ct][kt], acc[ct], 0, 0, 0);
    }
#pragma unroll
    for (int ct = 0; ct < 8; ct++) {
        int col = ct * 16 + lid;
        float bv = bf2f(bl[col]);
#pragma unroll
        for (int r = 0; r < 4; r++) {
            int rl = w * 16 + q * 4 + r;
            bf16 hv = f2bf(fmaxf(acc[ct][r] + bv, 0.f));
            T1[rl][col] = hv;
            int row = rowbase + rl;
            if (row < N) h1out[(size_t)row * 128 + col] = hv;
        }
    }
    __syncthreads();

    // ---- stage B: xp2 = relu(T1@Wp2^T + bp2) -> T2 ----
#pragma unroll
    for (int ct = 0; ct < 8; ct++) {
        int j = ct * 16 + lid;
#pragma unroll
        for (int kt = 0; kt < 4; kt++)
            bfrag[ct][kt] = *(const short8*)(Wp2 + (size_t)j * 128 + kt * 32 + q * 8);
    }
#pragma unroll
    for (int ct = 0; ct < 8; ct++) acc[ct] = (floatx4)(0.f);
#pragma unroll
    for (int kt = 0; kt < 4; kt++) {
        short8 af = *(const short8*)&T1[w * 16 + lid][kt * 32 + q * 8];
#pragma unroll
        for (int ct = 0; ct < 8; ct++)
            acc[ct] = __builtin_amdgcn_mfma_f32_16x16x32_bf16(af, bfrag[ct][kt], acc[ct], 0, 0, 0);
    }
#pragma unroll
    for (int ct = 0; ct < 8; ct++) {
        int col = ct * 16 + lid;
        float bv = bf2f(bp2[col]);
#pragma unroll
        for (int r = 0; r < 4; r++)
            T2[w * 16 + q * 4 + r][col] = f2bf(fmaxf(acc[ct][r] + bv, 0.f));
    }
    __syncthreads();

    // ---- stage C: Y2 chunks from T2, permuted store ----
#pragma unroll 1
    for (int cc = 0; cc < 4; cc++) {
#pragma unroll
        for (int ct = 0; ct < 8; ct++) {
            int j = cc * 128 + ct * 16 + lid;
#pragma unroll
            for (int kt = 0; kt < 4; kt++)
                bfrag[ct][kt] = *(const short8*)(Wih2 + (size_t)j * 128 + kt * 32 + q * 8);
        }
#pragma unroll
        for (int ct = 0; ct < 8; ct++) acc[ct] = (floatx4)(0.f);
#pragma unroll
        for (int kt = 0; kt < 4; kt++) {
            short8 af = *(const short8*)&T2[w * 16 + lid][kt * 32 + q * 8];
#pragma unroll
            for (int ct = 0; ct < 8; ct++)
                acc[ct] = __builtin_amdgcn_mfma_f32_16x16x32_bf16(af, bfrag[ct][kt], acc[ct], 0, 0, 0);
        }
#pragma unroll
        for (int ct = 0; ct < 8; ct++) {
            int cg = cc * 128 + ct * 16 + lid;
            float bv = bf2f(bih2[cg]) + bf2f(bhh2[cg]);
            int p = ypermute(cg);
#pragma unroll
            for (int r = 0; r < 4; r++) {
                int row = rowbase + w * 16 + q * 4 + r;
                if (row < N) Yout[(size_t)row * 512 + p] = f2bf(acc[ct][r] + bv);
            }
        }
    }
}

// ---------------------------------------------------------------------------
// LSTM neighbor aggregation (permuted Y). Block = 16 nodes, 256 thr, 2 blocks/CU
// (3 spilled -> r8 regression). Per step: wave w DMAs rows srcl[t+1][4j+w] into
// the LDS stage; consumer reads one conflict-free ds_read_b128 per gate.
// ---------------------------------------------------------------------------
__global__ __launch_bounds__(256, 2) void lstm_aggr(
    const bf16* __restrict__ Y,     // [N,512] PERMUTED pre-activations
    const int* __restrict__ esrc,   // [N,16]
    const bf16* __restrict__ Whh,   // [512,128]
    bf16* __restrict__ aggr,        // [N,128] out: final h
    int N)
{
    __shared__ alignas(16) short stage[2][16][520];  // 1040B row stride
    __shared__ alignas(16) bf16 hb[2][16][136];
    __shared__ int srcl[16][16];    // [t][node]

    const int tid = threadIdx.x;
    const int w = tid >> 6, l = tid & 63, q = l >> 4, lid = l & 15;
    const int nodebase = blockIdx.x * 16;   // N = 50000 = 3125*16, exact

    {
        int node = tid >> 4, t = tid & 15;
        srcl[t][node] = esrc[(size_t)(nodebase + node) * 16 + t];
    }
    for (int i = tid; i < 16 * 136; i += 256) ((short*)hb[0])[i] = 0;

    // Whh A-fragments: wf[hl][g][kt]; A-row = gatecol = (2w+hl+8g)*16 + lid
    short8 wf[2][4][4];
#pragma unroll
    for (int hl = 0; hl < 2; hl++)
#pragma unroll
        for (int g = 0; g < 4; g++) {
            int gc = (2 * w + hl + 8 * g) * 16 + lid;
#pragma unroll
            for (int kt = 0; kt < 4; kt++)
                wf[hl][g][kt] = *(const short8*)(Whh + (size_t)gc * 128 + kt * 32 + q * 8);
        }

    float c[2][4];
#pragma unroll
    for (int hl = 0; hl < 2; hl++)
#pragma unroll
        for (int r = 0; r < 4; r++) c[hl][r] = 0.f;

    __syncthreads();   // srcl visible before first DMA

    // prologue: DMA t=0 rows into stage[0] (wave w fetches rows 4j+w)
#pragma unroll
    for (int j = 0; j < 4; j++) {
        int r = 4 * j + w;
        int s = srcl[0][r];
        row_dma(Y + (size_t)s * 512 + l * 8, &stage[0][r][0]);
    }
    __syncthreads();   // drains vmcnt: stage[0] landed

#pragma unroll 2
    for (int t = 0; t < 16; t++) {
        const int cb = t & 1, nb = cb ^ 1;

        // issue DMA for t+1 first — in flight across the whole step
        if (t < 15) {
#pragma unroll
            for (int j = 0; j < 4; j++) {
                int r = 4 * j + w;
                int s = srcl[t + 1][r];
                row_dma(Y + (size_t)s * 512 + l * 8, &stage[nb][r][0]);
            }
        }

        // acc init: one b128 per gate (conflict-free), values {hl0 r0..3, hl1 r0..3}
        floatx4 acc[2][4];
#pragma unroll
        for (int g = 0; g < 4; g++) {
            short8 yv = *(const short8*)&stage[cb][lid][w * 128 + q * 32 + g * 8];
#pragma unroll
            for (int hl = 0; hl < 2; hl++)
#pragma unroll
                for (int r = 0; r < 4; r++)
                    acc[hl][g][r] = bfs2f(yv[hl * 4 + r]);
        }

        // G^T += Whh * h^T : B-frag = h[node=lid][k] via ds_read_b128
#pragma unroll
        for (int kt = 0; kt < 4; kt++) {
            short8 bh = *(const short8*)&hb[cb][lid][kt * 32 + q * 8];
#pragma unroll
            for (int hl = 0; hl < 2; hl++)
#pragma unroll
                for (int g = 0; g < 4; g++)
                    acc[hl][g] = __builtin_amdgcn_mfma_f32_16x16x32_bf16(wf[hl][g][kt], bh, acc[hl][g], 0, 0, 0);
        }

        // gates; h' cols hc = 32w+16hl+q*4+r for node lid
#pragma unroll
        for (int hl = 0; hl < 2; hl++) {
            short4v hv;
#pragma unroll
            for (int r = 0; r < 4; r++)
                hv[r] = f2bfs(cell(acc[hl][0][r], acc[hl][1][r], acc[hl][2][r], acc[hl][3][r], c[hl][r]));
            if (t < 15) *(short4v*)&hb[nb][lid][32 * w + 16 * hl + 4 * q] = hv;
            else        *(short4v*)(aggr + (size_t)(nodebase + lid) * 128 + 32 * w + 16 * hl + 4 * q) = hv;
        }

        __syncthreads();   // orders hb swap AND guarantees t+1 DMA landed
    }
}

extern "C" void kernel_launch(void* const* d_in, const int* in_sizes, int n_in,
                              void* d_out, int out_size, void* d_ws, size_t ws_size,
                              hipStream_t stream)
{
    const int N = 50000;
    const int* es = (const int*)d_in[1];
    char* ws = (char*)d_ws;

    // converted bf16 copies of the 19 used float tensors @[0,15MB)
    static const int idxs[19] = {0, 8,9,10,11,12,13,14,15,16, 17,18,19,20,21,22,23,24,25};
    bf16* conv[19];
    size_t off = 0;
    CvtAll ca;
    for (int k = 0; k < 19; k++) {
        conv[k] = (bf16*)ws + off;
        ca.t[k].src = d_in[idxs[k]];
        ca.t[k].dst = conv[k];
        ca.t[k].n = in_sizes[idxs[k]];
        off += (size_t)((in_sizes[idxs[k]] + 63) & ~63);
    }
    int* flag = (int*)(ws + ((size_t)15 << 20));
    bf16* aggr = (bf16*)(ws + ((size_t)16 << 20));   // [N,128]
    bf16* Y    = (bf16*)(ws + ((size_t)30 << 20));   // [N,512] permuted
    bf16* h1   = (bf16*)(ws + ((size_t)84 << 20));   // [N,128]

    const bf16 *xc  = conv[0];
    const bf16 *Wp1 = conv[1],  *bp1 = conv[2],  *Wih1 = conv[3],  *Whh1 = conv[4];
    const bf16 *bih1 = conv[5], *bhh1 = conv[6], *Wl1 = conv[7],   *bl1 = conv[8],  *Wr1 = conv[9];
    const bf16 *Wp2 = conv[10], *bp2 = conv[11], *Wih2 = conv[12], *Whh2 = conv[13];
    const bf16 *bih2 = conv[14], *bhh2 = conv[15], *Wl2 = conv[16], *bl2 = conv[17], *Wr2 = conv[18];

    dim3 blk(256);
    const int gx = (N + 63) / 64;    // 782
    const int gl = N / 16;           // 3125 (exact)

    detect_dtype<<<dim3(1), dim3(64), 0, stream>>>((const unsigned short*)d_in[0], flag);
    convert_inputs<<<dim3(1024), blk, 0, stream>>>(ca, flag);

    // ---- layer 1 ----
    fused_xp_y<<<dim3(gx), blk, 0, stream>>>(xc, Wp1, bp1, Wih1, bih1, bhh1, Y, N);
    lstm_aggr<<<dim3(gl), blk, 0, stream>>>(Y, es, Whh1, aggr, N);

    // ---- between layers: lin1 -> xp2 -> Y2 ----
    fused_lin_xp_y<<<dim3(gx), blk, 0, stream>>>(
        aggr, Wl1, bl1, xc, Wr1, h1, Wp2, bp2, Wih2, bih2, bhh2, Y, N);
    lstm_aggr<<<dim3(gl), blk, 0, stream>>>(Y, es, Whh2, aggr, N);

    // ---- final: out = lin_l2(aggr) + bl2 + lin_r2(h1) ----
    gemm_bias<3, false, false, true, true><<<dim3(gx, 1), blk, 0, stream>>>(
        aggr, Wl2, bl2, nullptr, h1, Wr2, d_out, flag, N, 40, 40);
}

// Round 10
// 757.201 us; speedup vs baseline: 1.6224x; 1.0111x over previous
//
#include <hip/hip_runtime.h>
#include <hip/hip_bf16.h>

// GCN_5016521802361: 2x SAGEConv(aggr='lstm', project=True), N=50000, D=16, F=128, C=40.
// Round 10: lstm restructured to 512-thr blocks / 8 waves, wave owns 16 hidden cols:
// wf 128->64 VGPR, acc 32->16 -> fits 128-reg cap -> launch_bounds(512,4) gives
// 16 waves/CU (2x r9) to fill the 42% idle issue slots. New Y permute
// p = (hid>>4)*64 + ((hid>>2)&3)*16 + g*4 + (hid&3): thread's 16 gate-values are
// one contiguous 32B LDS chunk. Fused writers updated; all else frozen from r9.

typedef __hip_bfloat16 bf16;
typedef __attribute__((ext_vector_type(8))) short short8;
typedef __attribute__((ext_vector_type(4))) short short4v;
typedef __attribute__((ext_vector_type(4))) float floatx4;

__device__ __forceinline__ float bf2f(bf16 v) { return __bfloat162float(v); }
__device__ __forceinline__ bf16  f2bf(float v) { return __float2bfloat16(v); }
__device__ __forceinline__ float bfs2f(short s) {
    union { float f; unsigned u; } v; v.u = ((unsigned)(unsigned short)s) << 16; return v.f;
}
__device__ __forceinline__ short f2bfs(float v) {
    bf16 b = __float2bfloat16(v); return *(short*)&b;
}

// merged-rcp LSTM cell update (r6, absmax-neutral)
__device__ __forceinline__ float cell(float i_, float f_, float g_, float o_, float& c) {
    float ei = __expf(-i_), ef = __expf(-f_), eg = __expf(2.f * g_);
    float cn = c * __builtin_amdgcn_rcpf(1.f + ef)
             + (eg - 1.f) * __builtin_amdgcn_rcpf((1.f + ei) * (eg + 1.f));
    c = cn;
    float ec = __expf(2.f * cn), eo = __expf(-o_);
    return (ec - 1.f) * __builtin_amdgcn_rcpf((ec + 1.f) * (1.f + eo));
}

// Y column permutation (512-thr lstm layout):
// cg = gate*128 + hid; w=hid>>4 (0..7), q=(hid>>2)&3, r=hid&3 -> p = w*64+q*16+g*4+r
__device__ __forceinline__ int ypermute(int cg) {
    int g = cg >> 7, hid = cg & 127;
    return ((hid >> 4) << 6) | (((hid >> 2) & 3) << 4) | (g << 2) | (hid & 3);
}

// direct global->LDS DMA, 16B per lane (global_load_lds_dwordx4)
__device__ __forceinline__ void row_dma(const bf16* gp, void* lp) {
    __builtin_amdgcn_global_load_lds(
        (const __attribute__((address_space(1))) void*)gp,
        (__attribute__((address_space(3))) void*)lp, 16, 0, 0);
}

__global__ void detect_dtype(const unsigned short* __restrict__ xb, int* __restrict__ flag) {
    int cnt = 0;
    for (int i = threadIdx.x; i < 1024; i += 64) {
        int e = (xb[i] >> 7) & 0xFF;
        cnt += (e >= 0xC8);
    }
#pragma unroll
    for (int off = 32; off; off >>= 1) cnt += __shfl_down(cnt, off);
    if (threadIdx.x == 0) *flag = (cnt >= 16) ? 1 : 0;   // 1 => inputs are float32
}

struct Cvt { const void* src; bf16* dst; int n; };
struct CvtAll { Cvt t[19]; };

__global__ void convert_inputs(CvtAll ca, const int* __restrict__ flag) {
    const bool isf32 = (*flag != 0);
    const int stride = gridDim.x * blockDim.x;
    const int tid0 = blockIdx.x * blockDim.x + threadIdx.x;
#pragma unroll 1
    for (int k = 0; k < 19; k++) {
        const int n = ca.t[k].n;
        const float* sf = (const float*)ca.t[k].src;
        const bf16*  sb = (const bf16*)ca.t[k].src;
        bf16* d = ca.t[k].dst;
        for (int i = tid0; i < n; i += stride)
            d[i] = isf32 ? f2bf(sf[i]) : sb[i];
    }
}

// generic (final lin2 layer)
template <int NCT, bool RELU, bool BIAS2, bool DUAL, bool OUTF>
__global__ __launch_bounds__(256, 2) void gemm_bias(
    const bf16* __restrict__ A, const bf16* __restrict__ B,
    const bf16* __restrict__ bias, const bf16* __restrict__ bias2,
    const bf16* __restrict__ A2, const bf16* __restrict__ B2,
    void* __restrict__ Cv, const int* __restrict__ oflag,
    int N, int nbt, int ldc)
{
    const int tid = threadIdx.x;
    const int w = tid >> 6, l = tid & 63, q = l >> 4, lid = l & 15;
    const int rowbase = blockIdx.x * 64 + w * 16;
    const int colslice = blockIdx.y * (NCT * 16);

    int arow = rowbase + lid;
    if (arow >= N) arow = N - 1;

    floatx4 acc[NCT];
#pragma unroll
    for (int ct = 0; ct < NCT; ct++) acc[ct] = (floatx4)(0.f);

    short8 bfrag[NCT][4];
#pragma unroll
    for (int ct = 0; ct < NCT; ct++) {
        int j = colslice + ct * 16 + lid;
        if (j >= nbt) j = nbt - 1;
#pragma unroll
        for (int kt = 0; kt < 4; kt++)
            bfrag[ct][kt] = *(const short8*)(B + (size_t)j * 128 + kt * 32 + q * 8);
    }
#pragma unroll
    for (int kt = 0; kt < 4; kt++) {
        short8 af = *(const short8*)(A + (size_t)arow * 128 + kt * 32 + q * 8);
#pragma unroll
        for (int ct = 0; ct < NCT; ct++)
            acc[ct] = __builtin_amdgcn_mfma_f32_16x16x32_bf16(af, bfrag[ct][kt], acc[ct], 0, 0, 0);
    }
    if constexpr (DUAL) {
#pragma unroll
        for (int ct = 0; ct < NCT; ct++) {
            int j = colslice + ct * 16 + lid;
            if (j >= nbt) j = nbt - 1;
#pragma unroll
            for (int kt = 0; kt < 4; kt++)
                bfrag[ct][kt] = *(const short8*)(B2 + (size_t)j * 128 + kt * 32 + q * 8);
        }
#pragma unroll
        for (int kt = 0; kt < 4; kt++) {
            short8 af = *(const short8*)(A2 + (size_t)arow * 128 + kt * 32 + q * 8);
#pragma unroll
            for (int ct = 0; ct < NCT; ct++)
                acc[ct] = __builtin_amdgcn_mfma_f32_16x16x32_bf16(af, bfrag[ct][kt], acc[ct], 0, 0, 0);
        }
    }
    bool of32 = false;
    if constexpr (OUTF) of32 = (*oflag != 0);
#pragma unroll
    for (int ct = 0; ct < NCT; ct++) {
        int cg = colslice + ct * 16 + lid;
        int cb = cg < nbt ? cg : nbt - 1;
        float bv = bf2f(bias[cb]);
        if constexpr (BIAS2) bv += bf2f(bias2[cb]);
#pragma unroll
        for (int r = 0; r < 4; r++) {
            int row = rowbase + q * 4 + r;
            float v = acc[ct][r] + bv;
            if constexpr (RELU) v = fmaxf(v, 0.f);
            if (row < N && cg < nbt) {
                size_t idx = (size_t)row * ldc + cg;
                if constexpr (OUTF) {
                    if (of32) ((float*)Cv)[idx] = v;
                    else      ((bf16*)Cv)[idx] = f2bf(v);
                } else {
                    ((bf16*)Cv)[idx] = f2bf(v);
                }
            }
        }
    }
}

// ---------------------------------------------------------------------------
// Fused chain, layer entry:  Y = (relu(X@Wp^T+bp)) @ Wih^T + bih + bhh, permuted.
// ---------------------------------------------------------------------------
__global__ __launch_bounds__(256, 2) void fused_xp_y(
    const bf16* __restrict__ X, const bf16* __restrict__ Wp, const bf16* __restrict__ bp,
    const bf16* __restrict__ Wih, const bf16* __restrict__ bih, const bf16* __restrict__ bhh,
    bf16* __restrict__ Yout, int N)
{
    __shared__ bf16 T[64][136];
    const int tid = threadIdx.x;
    const int w = tid >> 6, l = tid & 63, q = l >> 4, lid = l & 15;
    const int rowbase = blockIdx.x * 64;

    int arow = rowbase + w * 16 + lid;
    if (arow >= N) arow = N - 1;

    floatx4 acc[8];
    short8 bfrag[8][4];

    // ---- stage A: xp = relu(X@Wp^T + bp) -> T ----
#pragma unroll
    for (int ct = 0; ct < 8; ct++) acc[ct] = (floatx4)(0.f);
#pragma unroll
    for (int ct = 0; ct < 8; ct++) {
        int j = ct * 16 + lid;
#pragma unroll
        for (int kt = 0; kt < 4; kt++)
            bfrag[ct][kt] = *(const short8*)(Wp + (size_t)j * 128 + kt * 32 + q * 8);
    }
#pragma unroll
    for (int kt = 0; kt < 4; kt++) {
        short8 af = *(const short8*)(X + (size_t)arow * 128 + kt * 32 + q * 8);
#pragma unroll
        for (int ct = 0; ct < 8; ct++)
            acc[ct] = __builtin_amdgcn_mfma_f32_16x16x32_bf16(af, bfrag[ct][kt], acc[ct], 0, 0, 0);
    }
#pragma unroll
    for (int ct = 0; ct < 8; ct++) {
        int col = ct * 16 + lid;
        float bv = bf2f(bp[col]);
#pragma unroll
        for (int r = 0; r < 4; r++)
            T[w * 16 + q * 4 + r][col] = f2bf(fmaxf(acc[ct][r] + bv, 0.f));
    }
    __syncthreads();

    // ---- stage B: Y chunks (128 cols each), A from T, permuted store ----
#pragma unroll 1
    for (int cc = 0; cc < 4; cc++) {
#pragma unroll
        for (int ct = 0; ct < 8; ct++) {
            int j = cc * 128 + ct * 16 + lid;
#pragma unroll
            for (int kt = 0; kt < 4; kt++)
                bfrag[ct][kt] = *(const short8*)(Wih + (size_t)j * 128 + kt * 32 + q * 8);
        }
#pragma unroll
        for (int ct = 0; ct < 8; ct++) acc[ct] = (floatx4)(0.f);
#pragma unroll
        for (int kt = 0; kt < 4; kt++) {
            short8 af = *(const short8*)&T[w * 16 + lid][kt * 32 + q * 8];
#pragma unroll
            for (int ct = 0; ct < 8; ct++)
                acc[ct] = __builtin_amdgcn_mfma_f32_16x16x32_bf16(af, bfrag[ct][kt], acc[ct], 0, 0, 0);
        }
#pragma unroll
        for (int ct = 0; ct < 8; ct++) {
            int cg = cc * 128 + ct * 16 + lid;
            float bv = bf2f(bih[cg]) + bf2f(bhh[cg]);
            int p = ypermute(cg);
#pragma unroll
            for (int r = 0; r < 4; r++) {
                int row = rowbase + w * 16 + q * 4 + r;
                if (row < N) Yout[(size_t)row * 512 + p] = f2bf(acc[ct][r] + bv);
            }
        }
    }
}

// ---------------------------------------------------------------------------
// Fused chain, between layers: h1 = relu(aggr@Wl^T+bl+X@Wr^T) (global+LDS);
// xp2 = relu(h1@Wp2^T+bp2) (LDS); Y2 = xp2@Wih2^T+bih2+bhh2 (permuted store).
// ---------------------------------------------------------------------------
__global__ __launch_bounds__(256, 2) void fused_lin_xp_y(
    const bf16* __restrict__ aggr, const bf16* __restrict__ Wl, const bf16* __restrict__ bl,
    const bf16* __restrict__ X, const bf16* __restrict__ Wr,
    bf16* __restrict__ h1out,
    const bf16* __restrict__ Wp2, const bf16* __restrict__ bp2,
    const bf16* __restrict__ Wih2, const bf16* __restrict__ bih2, const bf16* __restrict__ bhh2,
    bf16* __restrict__ Yout, int N)
{
    __shared__ bf16 T1[64][136];
    __shared__ bf16 T2[64][136];
    const int tid = threadIdx.x;
    const int w = tid >> 6, l = tid & 63, q = l >> 4, lid = l & 15;
    const int rowbase = blockIdx.x * 64;

    int arow = rowbase + w * 16 + lid;
    if (arow >= N) arow = N - 1;

    floatx4 acc[8];
    short8 bfrag[8][4];

    // ---- stage A: h1 = relu(aggr@Wl^T + X@Wr^T + bl) -> T1 + global ----
#pragma unroll
    for (int ct = 0; ct < 8; ct++) acc[ct] = (floatx4)(0.f);
#pragma unroll
    for (int ct = 0; ct < 8; ct++) {
        int j = ct * 16 + lid;
#pragma unroll
        for (int kt = 0; kt < 4; kt++)
            bfrag[ct][kt] = *(const short8*)(Wl + (size_t)j * 128 + kt * 32 + q * 8);
    }
#pragma unroll
    for (int kt = 0; kt < 4; kt++) {
        short8 af = *(const short8*)(aggr + (size_t)arow * 128 + kt * 32 + q * 8);
#pragma unroll
        for (int ct = 0; ct < 8; ct++)
            acc[ct] = __builtin_amdgcn_mfma_f32_16x16x32_bf16(af, bfrag[ct][kt], acc[ct], 0, 0, 0);
    }
#pragma unroll
    for (int ct = 0; ct < 8; ct++) {
        int j = ct * 16 + lid;
#pragma unroll
        for (int kt = 0; kt < 4; kt++)
            bfrag[ct][kt] = *(const short8*)(Wr + (size_t)j * 128 + kt * 32 + q * 8);
    }
#pragma unroll
    for (int kt = 0; kt < 4; kt++) {
        short8 af = *(const short8*)(X + (size_t)arow * 128 + kt * 32 + q * 8);
#pragma unroll
        for (int ct = 0; ct < 8; ct++)
            acc[ct] = __builtin_amdgcn_mfma_f32_16x16x32_bf16(af, bfrag[ct][kt], acc[ct], 0, 0, 0);
    }
#pragma unroll
    for (int ct = 0; ct < 8; ct++) {
        int col = ct * 16 + lid;
        float bv = bf2f(bl[col]);
#pragma unroll
        for (int r = 0; r < 4; r++) {
            int rl = w * 16 + q * 4 + r;
            bf16 hv = f2bf(fmaxf(acc[ct][r] + bv, 0.f));
            T1[rl][col] = hv;
            int row = rowbase + rl;
            if (row < N) h1out[(size_t)row * 128 + col] = hv;
        }
    }
    __syncthreads();

    // ---- stage B: xp2 = relu(T1@Wp2^T + bp2) -> T2 ----
#pragma unroll
    for (int ct = 0; ct < 8; ct++) {
        int j = ct * 16 + lid;
#pragma unroll
        for (int kt = 0; kt < 4; kt++)
            bfrag[ct][kt] = *(const short8*)(Wp2 + (size_t)j * 128 + kt * 32 + q * 8);
    }
#pragma unroll
    for (int ct = 0; ct < 8; ct++) acc[ct] = (floatx4)(0.f);
#pragma unroll
    for (int kt = 0; kt < 4; kt++) {
        short8 af = *(const short8*)&T1[w * 16 + lid][kt * 32 + q * 8];
#pragma unroll
        for (int ct = 0; ct < 8; ct++)
            acc[ct] = __builtin_amdgcn_mfma_f32_16x16x32_bf16(af, bfrag[ct][kt], acc[ct], 0, 0, 0);
    }
#pragma unroll
    for (int ct = 0; ct < 8; ct++) {
        int col = ct * 16 + lid;
        float bv = bf2f(bp2[col]);
#pragma unroll
        for (int r = 0; r < 4; r++)
            T2[w * 16 + q * 4 + r][col] = f2bf(fmaxf(acc[ct][r] + bv, 0.f));
    }
    __syncthreads();

    // ---- stage C: Y2 chunks from T2, permuted store ----
#pragma unroll 1
    for (int cc = 0; cc < 4; cc++) {
#pragma unroll
        for (int ct = 0; ct < 8; ct++) {
            int j = cc * 128 + ct * 16 + lid;
#pragma unroll
            for (int kt = 0; kt < 4; kt++)
                bfrag[ct][kt] = *(const short8*)(Wih2 + (size_t)j * 128 + kt * 32 + q * 8);
        }
#pragma unroll
        for (int ct = 0; ct < 8; ct++) acc[ct] = (floatx4)(0.f);
#pragma unroll
        for (int kt = 0; kt < 4; kt++) {
            short8 af = *(const short8*)&T2[w * 16 + lid][kt * 32 + q * 8];
#pragma unroll
            for (int ct = 0; ct < 8; ct++)
                acc[ct] = __builtin_amdgcn_mfma_f32_16x16x32_bf16(af, bfrag[ct][kt], acc[ct], 0, 0, 0);
        }
#pragma unroll
        for (int ct = 0; ct < 8; ct++) {
            int cg = cc * 128 + ct * 16 + lid;
            float bv = bf2f(bih2[cg]) + bf2f(bhh2[cg]);
            int p = ypermute(cg);
#pragma unroll
            for (int r = 0; r < 4; r++) {
                int row = rowbase + w * 16 + q * 4 + r;
                if (row < N) Yout[(size_t)row * 512 + p] = f2bf(acc[ct][r] + bv);
            }
        }
    }
}

// ---------------------------------------------------------------------------
// LSTM neighbor aggregation (permuted Y), 512 threads / 8 waves / 16 nodes.
// Wave w owns hidden cols [16w,16w+16): wf[g][kt] = Whh rows (g*128+16w)+lid,
// 64 VGPRs. Transposed MFMA: C[row=hidcol-offset(q*4+r)][col=node(lid)].
// Per step: wave w DMAs Y rows {2w,2w+1} (1KB each) into stage; each thread
// reads its 16 gate-values as 2 contiguous ds_read_b128 (new permute);
// 4 cells/thread. launch_bounds(512,4) -> 2 blocks/CU = 16 waves/CU.
// ---------------------------------------------------------------------------
__global__ __launch_bounds__(512, 4) void lstm_aggr(
    const bf16* __restrict__ Y,     // [N,512] PERMUTED pre-activations
    const int* __restrict__ esrc,   // [N,16]
    const bf16* __restrict__ Whh,   // [512,128]
    bf16* __restrict__ aggr,        // [N,128] out: final h
    int N)
{
    __shared__ alignas(16) short stage[2][16][520];  // 1040B row stride
    __shared__ alignas(16) bf16 hb[2][16][136];
    __shared__ int srcl[16][16];    // [t][node]

    const int tid = threadIdx.x;
    const int w = tid >> 6, l = tid & 63, q = l >> 4, lid = l & 15;
    const int nodebase = blockIdx.x * 16;   // N = 50000 = 3125*16, exact

    if (tid < 256) {
        int node = tid >> 4, t = tid & 15;
        srcl[t][node] = esrc[(size_t)(nodebase + node) * 16 + t];
    }
    for (int i = tid; i < 16 * 136; i += 512) ((short*)hb[0])[i] = 0;

    // Whh A-fragments: wf[g][kt]; A-row = gatecol = g*128 + 16*w + lid
    short8 wf[4][4];
#pragma unroll
    for (int g = 0; g < 4; g++) {
        int gc = g * 128 + 16 * w + lid;
#pragma unroll
        for (int kt = 0; kt < 4; kt++)
            wf[g][kt] = *(const short8*)(Whh + (size_t)gc * 128 + kt * 32 + q * 8);
    }

    float c[4];
#pragma unroll
    for (int r = 0; r < 4; r++) c[r] = 0.f;

    __syncthreads();   // srcl visible before first DMA

    // prologue: DMA t=0 rows into stage[0] (wave w fetches rows 2w, 2w+1)
#pragma unroll
    for (int j = 0; j < 2; j++) {
        int r = 2 * w + j;
        int s = srcl[0][r];
        row_dma(Y + (size_t)s * 512 + l * 8, &stage[0][r][0]);
    }
    __syncthreads();   // drains vmcnt: stage[0] landed

#pragma unroll 2
    for (int t = 0; t < 16; t++) {
        const int cb = t & 1, nb = cb ^ 1;

        // issue DMA for t+1 first — in flight across the whole step
        if (t < 15) {
#pragma unroll
            for (int j = 0; j < 2; j++) {
                int r = 2 * w + j;
                int s = srcl[t + 1][r];
                row_dma(Y + (size_t)s * 512 + l * 8, &stage[nb][r][0]);
            }
        }

        // acc init: thread's 16 gate-values = 32B contiguous at stage[lid][w*64+q*16]
        floatx4 acc[4];
        {
            short8 y0 = *(const short8*)&stage[cb][lid][w * 64 + q * 16];
            short8 y1 = *(const short8*)&stage[cb][lid][w * 64 + q * 16 + 8];
#pragma unroll
            for (int g = 0; g < 2; g++)
#pragma unroll
                for (int r = 0; r < 4; r++) {
                    acc[g][r]     = bfs2f(y0[g * 4 + r]);
                    acc[2 + g][r] = bfs2f(y1[g * 4 + r]);
                }
        }

        // G^T += Whh * h^T : B-frag = h[node=lid][k] via ds_read_b128
#pragma unroll
        for (int kt = 0; kt < 4; kt++) {
            short8 bh = *(const short8*)&hb[cb][lid][kt * 32 + q * 8];
#pragma unroll
            for (int g = 0; g < 4; g++)
                acc[g] = __builtin_amdgcn_mfma_f32_16x16x32_bf16(wf[g][kt], bh, acc[g], 0, 0, 0);
        }

        // gates; h' cols = 16w + 4q + r for node lid
        {
            short4v hv;
#pragma unroll
            for (int r = 0; r < 4; r++)
                hv[r] = f2bfs(cell(acc[0][r], acc[1][r], acc[2][r], acc[3][r], c[r]));
            if (t < 15) *(short4v*)&hb[nb][lid][16 * w + 4 * q] = hv;
            else        *(short4v*)(aggr + (size_t)(nodebase + lid) * 128 + 16 * w + 4 * q) = hv;
        }

        __syncthreads();   // orders hb swap AND guarantees t+1 DMA landed
    }
}

extern "C" void kernel_launch(void* const* d_in, const int* in_sizes, int n_in,
                              void* d_out, int out_size, void* d_ws, size_t ws_size,
                              hipStream_t stream)
{
    const int N = 50000;
    const int* es = (const int*)d_in[1];
    char* ws = (char*)d_ws;

    // converted bf16 copies of the 19 used float tensors @[0,15MB)
    static const int idxs[19] = {0, 8,9,10,11,12,13,14,15,16, 17,18,19,20,21,22,23,24,25};
    bf16* conv[19];
    size_t off = 0;
    CvtAll ca;
    for (int k = 0; k < 19; k++) {
        conv[k] = (bf16*)ws + off;
        ca.t[k].src = d_in[idxs[k]];
        ca.t[k].dst = conv[k];
        ca.t[k].n = in_sizes[idxs[k]];
        off += (size_t)((in_sizes[idxs[k]] + 63) & ~63);
    }
    int* flag = (int*)(ws + ((size_t)15 << 20));
    bf16* aggr = (bf16*)(ws + ((size_t)16 << 20));   // [N,128]
    bf16* Y    = (bf16*)(ws + ((size_t)30 << 20));   // [N,512] permuted
    bf16* h1   = (bf16*)(ws + ((size_t)84 << 20));   // [N,128]

    const bf16 *xc  = conv[0];
    const bf16 *Wp1 = conv[1],  *bp1 = conv[2],  *Wih1 = conv[3],  *Whh1 = conv[4];
    const bf16 *bih1 = conv[5], *bhh1 = conv[6], *Wl1 = conv[7],   *bl1 = conv[8],  *Wr1 = conv[9];
    const bf16 *Wp2 = conv[10], *bp2 = conv[11], *Wih2 = conv[12], *Whh2 = conv[13];
    const bf16 *bih2 = conv[14], *bhh2 = conv[15], *Wl2 = conv[16], *bl2 = conv[17], *Wr2 = conv[18];

    dim3 blk(256);
    const int gx = (N + 63) / 64;    // 782
    const int gl = N / 16;           // 3125 (exact)

    detect_dtype<<<dim3(1), dim3(64), 0, stream>>>((const unsigned short*)d_in[0], flag);
    convert_inputs<<<dim3(1024), blk, 0, stream>>>(ca, flag);

    // ---- layer 1 ----
    fused_xp_y<<<dim3(gx), blk, 0, stream>>>(xc, Wp1, bp1, Wih1, bih1, bhh1, Y, N);
    lstm_aggr<<<dim3(gl), dim3(512), 0, stream>>>(Y, es, Whh1, aggr, N);

    // ---- between layers: lin1 -> xp2 -> Y2 ----
    fused_lin_xp_y<<<dim3(gx), blk, 0, stream>>>(
        aggr, Wl1, bl1, xc, Wr1, h1, Wp2, bp2, Wih2, bih2, bhh2, Y, N);
    lstm_aggr<<<dim3(gl), dim3(512), 0, stream>>>(Y, es, Whh2, aggr, N);

    // ---- final: out = lin_l2(aggr) + bl2 + lin_r2(h1) ----
    gemm_bias<3, false, false, true, true><<<dim3(gx, 1), blk, 0, stream>>>(
        aggr, Wl2, bl2, nullptr, h1, Wr2, d_out, flag, N, 40, 40);
}